// Round 1
// 424.989 us; speedup vs baseline: 1.0246x; 1.0246x over previous
//
#include <hip/hip_runtime.h>
#include <stdint.h>

// UnarySqrt scan, T=64 steps, N=2^20 channels, exact {0,1} floats.
//   per step: p = x*(1-tr); out = tr + p; tr' = p
// On {0,1} data this is 1-bit logic: out = tr|x ; tr' = x & ~tr.
//
// R15: phase-separated bitpack pipeline.
// R1..R14 established: every MIXED read+write structure lands at ~165 us
// (~3.1 TB/s) while the harness's pure-write fill sustains 6.5 TB/s in the
// same timed graph. Hint polarity is inert (437.6 vs 435.5). The untried
// axis is stream separation: because the data is 1-bit, the 256 MB output
// compresses to 8 MB (64 bits/column).
//   Phase 1 (pure read):  stream 256 MB input, scan in registers, write
//                         8 MB packed bits to d_ws (stays in L2/L3).
//   Phase 2 (pure write): read 8 MB packed (cache-hit), expand, stream
//                         256 MB output.
// Predicted: kernel time 165 -> ~85-110 us total across both dispatches;
// dur_us 435 -> ~360-390. If both phases still cap at ~3.1 TB/s, the
// interleave theory is dead and the remainder is harness-bound.

typedef float v4f __attribute__((ext_vector_type(4)));
typedef uint32_t v4u __attribute__((ext_vector_type(4)));

// ---------------------------------------------------------------- phase 1
// Pure-read pass: scan + pack. ws_lo[idx] = bits t=0..31 of the 4 columns
// in v4f-group idx; ws_hi[idx] = bits t=32..63.
__global__ __launch_bounds__(1024) void UnarySqrt_pack(
    const v4f* __restrict__ in,      // [64, stride]
    const v4f* __restrict__ trace0,  // [stride]
    v4u* __restrict__ ws_lo,         // [stride]
    v4u* __restrict__ ws_hi,         // [stride]
    int stride)
{
    const int idx = blockIdx.x * blockDim.x + threadIdx.x;
    if (idx >= stride) return;

    v4f t0 = trace0[idx];
    uint32_t tr[4];
    #pragma unroll
    for (int j = 0; j < 4; ++j) tr[j] = (t0[j] != 0.0f) ? 1u : 0u;

    v4u lo = {0u, 0u, 0u, 0u};
    #pragma unroll 8
    for (int t = 0; t < 32; ++t) {
        v4f x = __builtin_nontemporal_load(
            &in[(size_t)t * (size_t)stride + (size_t)idx]);
        #pragma unroll
        for (int j = 0; j < 4; ++j) {
            uint32_t xb = (x[j] != 0.0f) ? 1u : 0u;
            lo[j] |= (xb | tr[j]) << t;      // out bit
            tr[j] = xb & (tr[j] ^ 1u);       // JKFF: J=out, K=1
        }
    }
    v4u hi = {0u, 0u, 0u, 0u};
    #pragma unroll 8
    for (int t = 32; t < 64; ++t) {
        v4f x = __builtin_nontemporal_load(
            &in[(size_t)t * (size_t)stride + (size_t)idx]);
        #pragma unroll
        for (int j = 0; j < 4; ++j) {
            uint32_t xb = (x[j] != 0.0f) ? 1u : 0u;
            hi[j] |= (xb | tr[j]) << (t - 32);
            tr[j] = xb & (tr[j] ^ 1u);
        }
    }
    // Plain stores: 8 MB total, want it retained in L2/L3 for phase 2.
    ws_lo[idx] = lo;
    ws_hi[idx] = hi;
}

// ---------------------------------------------------------------- phase 2
// Pure-write pass: read packed bits (cache-resident), expand to floats.
__global__ __launch_bounds__(1024) void UnarySqrt_expand(
    const v4u* __restrict__ ws_lo,
    const v4u* __restrict__ ws_hi,
    v4f* __restrict__ out,           // [64, stride]
    int stride)
{
    const int idx = blockIdx.x * blockDim.x + threadIdx.x;
    if (idx >= stride) return;

    v4u lo = ws_lo[idx];
    v4u hi = ws_hi[idx];

    #pragma unroll 8
    for (int t = 0; t < 32; ++t) {
        v4f o;
        #pragma unroll
        for (int j = 0; j < 4; ++j)
            o[j] = ((lo[j] >> t) & 1u) ? 1.0f : 0.0f;
        out[(size_t)t * (size_t)stride + (size_t)idx] = o;
    }
    #pragma unroll 8
    for (int t = 32; t < 64; ++t) {
        v4f o;
        #pragma unroll
        for (int j = 0; j < 4; ++j)
            o[j] = ((hi[j] >> (t - 32)) & 1u) ? 1.0f : 0.0f;
        out[(size_t)t * (size_t)stride + (size_t)idx] = o;
    }
}

// -------------------------------------------------- fallback: single pass
// (R14 best structure — correct for T==64 without workspace.)
__global__ __launch_bounds__(1024) void UnarySqrt_kernel(
    const v4f* __restrict__ in, const v4f* __restrict__ trace0,
    v4f* __restrict__ out, int stride)
{
    const int idx = blockIdx.x * blockDim.x + threadIdx.x;
    if (idx >= stride) return;

    v4f tr = trace0[idx];
    v4f x  = __builtin_nontemporal_load(&in[idx]);

    #pragma unroll 8
    for (int t = 0; t < 64; ++t) {
        v4f xn;
        if (t + 1 < 64) {
            xn = __builtin_nontemporal_load(
                &in[(size_t)(t + 1) * (size_t)stride + (size_t)idx]);
        }
        v4f p = x * (1.0f - tr);
        v4f o = tr + p;
        out[(size_t)t * (size_t)stride + (size_t)idx] = o;
        tr = p;
        x = xn;
    }
}

// Generic fallback (correct for any T, N%4==0, arbitrary float inputs).
__global__ __launch_bounds__(256) void UnarySqrt_generic(
    const v4f* __restrict__ in, const v4f* __restrict__ trace0,
    v4f* __restrict__ out, int stride, int T)
{
    int idx = blockIdx.x * blockDim.x + threadIdx.x;
    if (idx >= stride) return;
    v4f tr = trace0[idx];
    for (int t = 0; t < T; ++t) {
        v4f x = in[(size_t)t * stride + idx];
        v4f p = x * (1.0f - tr);
        out[(size_t)t * stride + idx] = tr + p;
        tr = p;
    }
}

extern "C" void kernel_launch(void* const* d_in, const int* in_sizes, int n_in,
                              void* d_out, int out_size, void* d_ws, size_t ws_size,
                              hipStream_t stream) {
    const float* bits   = (const float*)d_in[0];  // [T, N]
    const float* trace0 = (const float*)d_in[1];  // [N]

    int N = in_sizes[1];
    int T = in_sizes[0] / N;
    int stride = N / 4;

    size_t ws_needed = (size_t)stride * 2 * sizeof(v4u);  // 8 MB at N=2^20

    if (T == 64 && (stride % 1024) == 0 && d_ws && ws_size >= ws_needed) {
        int grid = stride / 1024;  // 256 blocks at N=2^20 -> 1 block/CU
        v4u* ws_lo = (v4u*)d_ws;
        v4u* ws_hi = ws_lo + stride;
        UnarySqrt_pack<<<grid, 1024, 0, stream>>>(
            (const v4f*)bits, (const v4f*)trace0, ws_lo, ws_hi, stride);
        UnarySqrt_expand<<<grid, 1024, 0, stream>>>(
            ws_lo, ws_hi, (v4f*)d_out, stride);
    } else if (T == 64 && (stride % 1024) == 0) {
        int grid = stride / 1024;
        UnarySqrt_kernel<<<grid, 1024, 0, stream>>>(
            (const v4f*)bits, (const v4f*)trace0, (v4f*)d_out, stride);
    } else {
        int block = 256;
        int grid = (stride + block - 1) / block;
        UnarySqrt_generic<<<grid, block, 0, stream>>>(
            (const v4f*)bits, (const v4f*)trace0, (v4f*)d_out, stride, T);
    }
}